// Round 2
// baseline (861.064 us; speedup 1.0000x reference)
//
#include <hip/hip_runtime.h>
#include <stdint.h>

#define NODE_DIM 128
#define GH 64
#define OUT_DIM 128
#define TM 128          // nodes per block in kernel 1
#define K2_ROWS 16      // graph rows per block in kernel 2

typedef float f32x4 __attribute__((ext_vector_type(4)));
typedef short s16x8 __attribute__((ext_vector_type(8)));

#define GLOBAL_AS __attribute__((address_space(1)))
#define LDS_AS __attribute__((address_space(3)))

__device__ __forceinline__ int imin(int a, int b) { return a < b ? a : b; }

// ---------------------------------------------------------------------------
// Kernel 0: pre-pack W_g1 [128][64] into MFMA B-fragment order, split bf16
// hi/lo (truncation split: hi = top16(x), lo = top16(x - hi), exact residual).
// Slot map (bijective in k, same map used for A at runtime, so the per-lane
// k-permutation cancels): combo = ks*4+nf; lane l, elem j holds
// B[k = ks*32 + (l>>4)*8 + j][col = nf*16 + (l&15)].
// ---------------------------------------------------------------------------
__global__ void prep_bfrag(const float* __restrict__ Wg1,
                           short* __restrict__ bhi, short* __restrict__ blo) {
    int tid = blockIdx.x * blockDim.x + threadIdx.x;   // 0..1023
    if (tid >= 1024) return;
    int combo = tid >> 6;
    int lane = tid & 63;
    int ks = combo >> 2, nf = combo & 3;
    int k0 = ks * 32 + (lane >> 4) * 8;
    int col = nf * 16 + (lane & 15);
    s16x8 vhi, vlo;
#pragma unroll
    for (int j = 0; j < 8; ++j) {
        float w = Wg1[(k0 + j) * GH + col];
        uint32_t b = __float_as_uint(w);
        float hf = __uint_as_float(b & 0xFFFF0000u);
        float l = w - hf;                      // exact
        vhi[j] = (short)(b >> 16);
        vlo[j] = (short)(__float_as_uint(l) >> 16);
    }
    ((s16x8*)bhi)[combo * 64 + lane] = vhi;
    ((s16x8*)blo)[combo * 64 + lane] = vlo;
}

// ---------------------------------------------------------------------------
// Kernel 1: per 128-node tile: hidden = h*Wg1 (split-bf16 MFMA, 3 passes:
// hi*hi + hi*lo + lo*hi, ~2^-18 rel err), gate = sigmoid(relu(hidden+b1)*W2
// + b2), then segmented accumulate of s[g] += gate*h and c[g] += gate
// (sorted batch -> run-length + one atomic per segment transition).
// LDS h tile is XOR-swizzled (byte bits 4-6 ^= node&7) via pre-swizzled
// global_load_lds SOURCE addresses (linear LDS dest, rule #21); all reads
// apply the same XOR. s accumulates directly into d_out.
// ---------------------------------------------------------------------------
__launch_bounds__(256, 2)
__global__ void gate_accum(const float* __restrict__ h,
                           const int* __restrict__ batch,
                           const float* __restrict__ bg1,
                           const float* __restrict__ wg2,
                           const float* __restrict__ bg2,
                           const short* __restrict__ bhi,
                           const short* __restrict__ blo,
                           float* __restrict__ sacc,
                           float* __restrict__ cacc,
                           int nnodes) {
    __shared__ float hbuf[TM * NODE_DIM];     // 64 KB, swizzled layout
    __shared__ float gate_lds[TM];
    __shared__ int batch_lds[TM];

    const int tid = threadIdx.x;
    const int lane = tid & 63;
    const int wave = tid >> 6;
    const int tile0 = blockIdx.x * TM;
    const int valid = imin(TM, nnodes - tile0);

    // ---- stage h tile: linear LDS dest, inverse-swizzled global source ----
    {
        const char* hbase = (const char*)(h + (size_t)tile0 * NODE_DIM);
#pragma unroll
        for (int i = 0; i < 16; ++i) {
            int d = i * 4096 + wave * 1024 + lane * 16;  // LDS byte offset
            int node = d >> 9;                            // 512 B per node row
            int o = d & 511;
            int osrc = o ^ ((node & 7) << 4);
            if (node < valid) {                           // wave-uniform (2 nodes/wave-step)
                const void* src = hbase + node * 512 + osrc;
                __builtin_amdgcn_global_load_lds(
                    (const GLOBAL_AS unsigned int*)src,
                    (LDS_AS unsigned int*)hbuf + (d >> 2), 16, 0, 0);
            }
        }
        if (tid < TM)
            batch_lds[tid] = (tid < valid) ? batch[tile0 + tid] : 0x7fffffff;
    }

    // per-lane gate-layer params (L1-hot scalar loads)
    float bg1_r[4], wg2_r[4];
#pragma unroll
    for (int nf = 0; nf < 4; ++nf) {
        bg1_r[nf] = bg1[nf * 16 + (lane & 15)];
        wg2_r[nf] = wg2[nf * 16 + (lane & 15)];
    }
    const float bg2v = bg2[0];

    __syncthreads();

    // ---- MFMA: hidden = h * Wg1, split-bf16 3-pass ----
    f32x4 acc[2][4];
#pragma unroll
    for (int st = 0; st < 2; ++st)
#pragma unroll
        for (int nf = 0; nf < 4; ++nf)
            acc[st][nf] = (f32x4)0.0f;

    const int wbase = wave * 32;   // this wave's 32 nodes (2 subtiles of 16)
    const s16x8* bhi8 = (const s16x8*)bhi;
    const s16x8* blo8 = (const s16x8*)blo;

#pragma unroll
    for (int ks = 0; ks < 4; ++ks) {
        s16x8 ahi[2], alo[2];
#pragma unroll
        for (int st = 0; st < 2; ++st) {
            int node = wbase + st * 16 + (lane & 15);
            int k0 = ks * 32 + (lane >> 4) * 8;
            int swz = (node & 7) << 4;
            int b0 = node * 512 + ((k0 * 4) ^ swz);
            int b1 = node * 512 + (((k0 + 4) * 4) ^ swz);
            f32x4 x0 = *(const f32x4*)((const char*)hbuf + b0);
            f32x4 x1 = *(const f32x4*)((const char*)hbuf + b1);
#pragma unroll
            for (int j = 0; j < 8; ++j) {
                float x = (j < 4) ? x0[j] : x1[j - 4];
                uint32_t bb = __float_as_uint(x);
                float hf = __uint_as_float(bb & 0xFFFF0000u);
                ahi[st][j] = (short)(bb >> 16);
                alo[st][j] = (short)(__float_as_uint(x - hf) >> 16);
            }
        }
#pragma unroll
        for (int nf = 0; nf < 4; ++nf) {
            s16x8 bh = bhi8[(ks * 4 + nf) * 64 + lane];
            s16x8 bl = blo8[(ks * 4 + nf) * 64 + lane];
#pragma unroll
            for (int st = 0; st < 2; ++st) {
                acc[st][nf] = __builtin_amdgcn_mfma_f32_16x16x32_bf16(ahi[st], bh, acc[st][nf], 0, 0, 0);
                acc[st][nf] = __builtin_amdgcn_mfma_f32_16x16x32_bf16(ahi[st], bl, acc[st][nf], 0, 0, 0);
                acc[st][nf] = __builtin_amdgcn_mfma_f32_16x16x32_bf16(alo[st], bh, acc[st][nf], 0, 0, 0);
            }
        }
    }

    // ---- gate: relu(hidden + b1) . w2, 16-lane butterfly, sigmoid ----
    // C layout (m89-verified): col = lane&15, row = (lane>>4)*4 + r
#pragma unroll
    for (int st = 0; st < 2; ++st) {
        float z[4] = {0.f, 0.f, 0.f, 0.f};
#pragma unroll
        for (int nf = 0; nf < 4; ++nf)
#pragma unroll
            for (int r = 0; r < 4; ++r) {
                float v = acc[st][nf][r] + bg1_r[nf];
                v = fmaxf(v, 0.0f);
                z[r] = fmaf(v, wg2_r[nf], z[r]);
            }
#pragma unroll
        for (int r = 0; r < 4; ++r) {
            float zz = z[r];
            zz += __shfl_xor(zz, 1);
            zz += __shfl_xor(zz, 2);
            zz += __shfl_xor(zz, 4);
            zz += __shfl_xor(zz, 8);
            float g = 1.0f / (1.0f + __expf(-(zz + bg2v)));
            if ((lane & 15) == 0)
                gate_lds[wbase + st * 16 + (lane >> 4) * 4 + r] = g;
        }
    }
    __syncthreads();

    // ---- segmented accumulate: s[g] += gate*h, c[g] += gate ----
    const int col = tid & 127;
    const int half = tid >> 7;
    const int n0 = half * 64;
    const int n1 = imin(n0 + 64, valid);
    float accv = 0.0f, gsum = 0.0f;
    int cur = -1;
    for (int n = n0; n < n1; ++n) {
        int g = batch_lds[n];
        if (g != cur) {                       // wave-uniform branch (n uniform)
            if (cur >= 0) {
                atomicAdd(&sacc[(size_t)cur * OUT_DIM + col], accv);
                if (col == 0) atomicAdd(&cacc[cur], gsum);
            }
            cur = g; accv = 0.0f; gsum = 0.0f;
        }
        float gate = gate_lds[n];
        int byteo = n * 512 + ((col * 4) ^ ((n & 7) << 4));
        float hv = *(const float*)((const char*)hbuf + byteo);
        accv = fmaf(gate, hv, accv);
        gsum += gate;
    }
    if (cur >= 0) {
        atomicAdd(&sacc[(size_t)cur * OUT_DIM + col], accv);
        if (col == 0) atomicAdd(&cacc[cur], gsum);
    }
}

// ---------------------------------------------------------------------------
// Kernel 2: out[r][c] = sum_k s[r][k]*Wp[k][c] + c[r]*bp[c]
// Runs IN-PLACE on d_out (stages its rows into LDS before overwriting).
// ---------------------------------------------------------------------------
__launch_bounds__(256)
__global__ void proj_out(const float* __restrict__ sacc,
                         const float* __restrict__ cacc,
                         const float* __restrict__ Wp,
                         const float* __restrict__ bp,
                         float* __restrict__ out) {
    __shared__ float s_lds[K2_ROWS * NODE_DIM];
    __shared__ float c_lds[K2_ROWS];
    const int tid = threadIdx.x;
    const int row0 = blockIdx.x * K2_ROWS;
#pragma unroll
    for (int i = 0; i < 8; ++i) {
        int idx = tid + i * 256;
        s_lds[idx] = sacc[(size_t)row0 * NODE_DIM + idx];
    }
    if (tid < K2_ROWS) c_lds[tid] = cacc[row0 + tid];
    __syncthreads();

    const int col = tid & 127;
    const int rh = tid >> 7;     // rows rh*8 .. rh*8+7
    const float bpv = bp[col];
    float o[8];
#pragma unroll
    for (int r = 0; r < 8; ++r) o[r] = c_lds[rh * 8 + r] * bpv;
    for (int k = 0; k < NODE_DIM; ++k) {
        float w = Wp[k * OUT_DIM + col];
#pragma unroll
        for (int r = 0; r < 8; ++r)
            o[r] = fmaf(s_lds[(rh * 8 + r) * NODE_DIM + k], w, o[r]);
    }
#pragma unroll
    for (int r = 0; r < 8; ++r)
        out[(size_t)(row0 + rh * 8 + r) * OUT_DIM + col] = o[r];
}

// ---------------------------------------------------------------------------
extern "C" void kernel_launch(void* const* d_in, const int* in_sizes, int n_in,
                              void* d_out, int out_size, void* d_ws, size_t ws_size,
                              hipStream_t stream) {
    const float* h = (const float*)d_in[0];
    const int* batch = (const int*)d_in[1];       // harness: integer -> int32
    const float* Wg1 = (const float*)d_in[2];
    const float* bg1 = (const float*)d_in[3];
    const float* wg2 = (const float*)d_in[4];
    const float* bg2 = (const float*)d_in[5];
    const float* Wp = (const float*)d_in[6];
    const float* bp = (const float*)d_in[7];
    float* out = (float*)d_out;

    const int nnodes = in_sizes[0] / NODE_DIM;
    const int ngraphs = out_size / OUT_DIM;

    // Workspace: bhi 16KB | blo 16KB | cacc ngraphs*4 (64KB). sacc = d_out.
    char* ws = (char*)d_ws;
    short* bhi = (short*)ws;
    short* blo = (short*)(ws + 16 * 1024);
    float* cacc = (float*)(ws + 32 * 1024);
    float* sacc = out;                            // accumulate gated sum in-place

    hipMemsetAsync(sacc, 0, (size_t)out_size * sizeof(float), stream);
    hipMemsetAsync(cacc, 0, (size_t)ngraphs * sizeof(float), stream);
    prep_bfrag<<<4, 256, 0, stream>>>(Wg1, bhi, blo);

    int nblk = (nnodes + TM - 1) / TM;
    gate_accum<<<nblk, 256, 0, stream>>>(h, batch, bg1, wg2, bg2,
                                         bhi, blo, sacc, cacc, nnodes);

    proj_out<<<ngraphs / K2_ROWS, 256, 0, stream>>>(sacc, cacc, Wp, bp, out);
}